// Round 1
// baseline (853.343 us; speedup 1.0000x reference)
//
#include <hip/hip_runtime.h>
#include <stdint.h>

// ---------------------------------------------------------------------------
// LIF layer, T=200 sequential steps over B*N = 262144 neurons.
// Bit-exact replication of the JAX reference:
//   - threefry2x32 PRNG, partitionable mode (JAX >= 0.4.36 default):
//       split(key, n):  key_i = threefry(key, (0, i))  (both output words)
//       random_bits32:  bits[e] = o0 ^ o1 of threefry(key, (0, e))
//   - uniform:  bitcast((bits>>9)|0x3f800000) - 1.0f
//   - normal:   sqrt(2) * erfinv(u * 2.0f + nextafter(-1,0))   (XLA Giles poly)
//   - sigmoid:  1 / (1 + exp(-x))        (XLA LogisticExpander)
//   - exp/log1p = __ocml_*_f32 (HIP expf/log1pf) — matches XLA-ROCm lowering
//   - NO fma contraction anywhere (XLA emits separate mul/add)
// ---------------------------------------------------------------------------

#define TSTEPS 200
#define BN     262144u            // 64 * 4096
#define TBN    ((size_t)TSTEPS * (size_t)BN)

// ---- threefry2x32, exactly JAX's 20-round schedule ----
__device__ __forceinline__ void tf2x32(uint32_t k0, uint32_t k1,
                                       uint32_t c0, uint32_t c1,
                                       uint32_t& o0, uint32_t& o1) {
  uint32_t ks2 = k0 ^ k1 ^ 0x1BD11BDAu;
  uint32_t x0 = c0 + k0, x1 = c1 + k1;
#define R1(r) { x0 += x1; x1 = (x1 << (r)) | (x1 >> (32 - (r))); x1 ^= x0; }
#define R4A R1(13) R1(15) R1(26) R1(6)
#define R4B R1(17) R1(29) R1(16) R1(24)
  R4A; x0 += k1;  x1 += ks2 + 1u;
  R4B; x0 += ks2; x1 += k0 + 2u;
  R4A; x0 += k0;  x1 += k1 + 3u;
  R4B; x0 += k1;  x1 += ks2 + 4u;
  R4A; x0 += ks2; x1 += k0 + 5u;
#undef R4A
#undef R4B
#undef R1
  o0 = x0; o1 = x1;
}

// ---- XLA erfinv (Giles polynomial), f32, no contraction ----
__device__ __forceinline__ float erfinv_f32(float x) {
#pragma clang fp contract(off)
  float w = -log1pf(-(x * x));
  float p;
  if (w < 5.0f) {
    w = w - 2.5f;
    p =  2.81022636e-08f;
    p =  3.43273939e-07f + p * w;
    p = -3.5233877e-06f  + p * w;
    p = -4.39150654e-06f + p * w;
    p =  0.00021858087f  + p * w;
    p = -0.00125372503f  + p * w;
    p = -0.00417768164f  + p * w;
    p =  0.246640727f    + p * w;
    p =  1.50140941f     + p * w;
  } else {
    w = sqrtf(w) - 3.0f;
    p = -0.000200214257f;
    p =  0.000100950558f + p * w;
    p =  0.00134934322f  + p * w;
    p = -0.00367342844f  + p * w;
    p =  0.00573950773f  + p * w;
    p = -0.0076224613f   + p * w;
    p =  0.00943887047f  + p * w;
    p =  1.00167406f     + p * w;
    p =  2.83297682f     + p * w;
  }
  return p * x;
}

__device__ __forceinline__ float u01(uint32_t b) {
#pragma clang fp contract(off)
  return __uint_as_float((b >> 9) | 0x3f800000u) - 1.0f;
}

// ---- per-step key derivation: keys = split(key(42), 200); kn,ks = split(keys[t]) ----
__global__ void keys_kernel(uint4* __restrict__ gK) {
  int t = blockIdx.x * blockDim.x + threadIdx.x;
  if (t >= TSTEPS) return;
  // master key(42) = (0, 42); partitionable fold-like split: counter = (0, t)
  uint32_t K0, K1; tf2x32(0u, 42u, 0u, (uint32_t)t, K0, K1);
  uint32_t n0, n1; tf2x32(K0, K1, 0u, 0u, n0, n1);   // k_noise = row 0
  uint32_t s0, s1; tf2x32(K0, K1, 0u, 1u, s0, s1);   // k_spike = row 1
  gK[t] = make_uint4(n0, n1, s0, s1);
}

__global__ __launch_bounds__(256) void lif_kernel(
    const float* __restrict__ gI,
    const float* __restrict__ gV0, const float* __restrict__ gT0,
    const float* __restrict__ gA0, const float* __restrict__ gS0,
    const float* __restrict__ gN0,
    const uint4* __restrict__ gK,
    float* __restrict__ gOut)
{
#pragma clang fp contract(off)
  __shared__ uint4 kt[TSTEPS];
  for (int i = threadIdx.x; i < TSTEPS; i += 256) kt[i] = gK[i];
  __syncthreads();

  const uint32_t e = blockIdx.x * 256u + threadIdx.x;
  const float LO = -0x1.fffffep-1f;          // nextafter(-1, 0) in f32
  const float SQRT2 = 1.4142135623730951f;   // rounds to 0x3FB504F3

  float V  = gV0[e];
  float Th = gT0[e];
  float Ad = gA0[e];
  float Sy = gS0[e];
  float Nm = gN0[e];

  const float* Ip = gI + e;
  float* So = gOut + e;          // spikes (as 0.0/1.0 float), T*B*N
  float* Vo = gOut + TBN + e;    // voltages, T*B*N

  for (int t = 0; t < TSTEPS; ++t) {
    uint4 k = kt[t];
    size_t off = (size_t)t * BN;
    float I = Ip[off];

    // noise = normal(k_noise) * 0.1
    uint32_t b0, b1; tf2x32(k.x, k.y, 0u, e, b0, b1);
    float un = u01(b0 ^ b1);
    float x = un * 2.0f + LO;          // u * (hi - lo) + lo, span == 2.0f exactly
    x = fmaxf(LO, x);
    float nrm = SQRT2 * erfinv_f32(x);
    float noise = nrm * 0.1f;

    // V update: V + (I_eff - V) * (DT/TAU) + noise
    float Ieff = (I * Sy + Nm) - Ad;
    V = (V + (Ieff - V) * 0.05f) + noise;

    // spike prob = 1 / (1 + exp(-(V - Th)))
    float d = V - Th;
    float ex = expf(-d);
    float p = 1.0f / (1.0f + ex);

    // uniform(k_spike) < p
    uint32_t c0, c1; tf2x32(k.z, k.w, 0u, e, c0, c1);
    float us = u01(c0 ^ c1);
    us = fmaxf(0.0f, us);              // lax.max(minval=0, u*1+0)
    bool spk = us < p;
    float sf = spk ? 1.0f : 0.0f;

    V = spk ? 0.0f : V;                               // where(spikes, V_RESET, V)
    float thn = Th - 0.1f * (Th - 1.0f);
    Th = spk ? (Th + 0.1f) : thn;                     // where(spikes, Th+ETA, relax)
    Th = fminf(fmaxf(Th, 0.5f), 2.0f);                // clip
    Ad = Ad * 0.9f + 0.5f * sf;
    Sy = Sy * (1.0f - 0.1f * sf) + 0.05f * (1.0f - Sy);

    So[off] = sf;
    Vo[off] = V;
  }
}

extern "C" void kernel_launch(void* const* d_in, const int* in_sizes, int n_in,
                              void* d_out, int out_size, void* d_ws, size_t ws_size,
                              hipStream_t stream) {
  const float* I    = (const float*)d_in[0];
  const float* V0   = (const float*)d_in[1];
  const float* Vth0 = (const float*)d_in[2];
  const float* ad0  = (const float*)d_in[3];
  const float* sy0  = (const float*)d_in[4];
  const float* nm0  = (const float*)d_in[5];
  float* out = (float*)d_out;
  uint4* ktab = (uint4*)d_ws;   // 200 * 16 B = 3.2 KB of workspace

  keys_kernel<<<1, 256, 0, stream>>>(ktab);
  lif_kernel<<<BN / 256, 256, 0, stream>>>(I, V0, Vth0, ad0, sy0, nm0, ktab, out);
}

// Round 3
// 848.802 us; speedup vs baseline: 1.0053x; 1.0053x over previous
//
#include <hip/hip_runtime.h>
#include <stdint.h>

// ---------------------------------------------------------------------------
// LIF layer, T=200 sequential steps over B*N = 262144 neurons.
// Bit-exact replication of the JAX reference (verified round 1: absmax 2^-7,
// zero spike flips). All float arithmetic must stay byte-identical:
//   - threefry2x32, partitionable mode
//   - uniform:  bitcast((bits>>9)|0x3f800000) - 1.0f
//   - normal:   sqrt(2) * erfinv(u * 2.0f + nextafter(-1,0))  (XLA Giles poly)
//   - sigmoid:  1 / (1 + exp(-x)),  exp/log1p = OCML
//   - NO fma contraction anywhere
//
// Round 2 (resubmitted round 3 after broker timeout): software-pipeline.
// noise(t), us(t) depend only on (t,e) — compute them one step AHEAD so the
// ~190 independent ops interleave into the serial ~40-op state-update chain's
// latency bubbles. Keys scalarized to SGPRs via readfirstlane.
// ---------------------------------------------------------------------------

#define TSTEPS 200
#define BN     262144u            // 64 * 4096
#define TBN    ((size_t)TSTEPS * (size_t)BN)

// ---- threefry2x32, exactly JAX's 20-round schedule; keys wave-uniform ----
__device__ __forceinline__ void tf2x32(uint32_t k0, uint32_t k1,
                                       uint32_t c0, uint32_t c1,
                                       uint32_t& o0, uint32_t& o1) {
  uint32_t ks2 = k0 ^ k1 ^ 0x1BD11BDAu;
  uint32_t x0 = c0 + k0, x1 = c1 + k1;
#define R1(r) { x0 += x1; x1 = (x1 << (r)) | (x1 >> (32 - (r))); x1 ^= x0; }
#define R4A R1(13) R1(15) R1(26) R1(6)
#define R4B R1(17) R1(29) R1(16) R1(24)
  R4A; x0 += k1;  x1 += ks2 + 1u;
  R4B; x0 += ks2; x1 += k0 + 2u;
  R4A; x0 += k0;  x1 += k1 + 3u;
  R4B; x0 += k1;  x1 += ks2 + 4u;
  R4A; x0 += ks2; x1 += k0 + 5u;
#undef R4A
#undef R4B
#undef R1
  o0 = x0; o1 = x1;
}

// ---- XLA erfinv (Giles polynomial), f32, no contraction ----
__device__ __forceinline__ float erfinv_f32(float x) {
#pragma clang fp contract(off)
  float w = -log1pf(-(x * x));
  float p;
  if (w < 5.0f) {
    w = w - 2.5f;
    p =  2.81022636e-08f;
    p =  3.43273939e-07f + p * w;
    p = -3.5233877e-06f  + p * w;
    p = -4.39150654e-06f + p * w;
    p =  0.00021858087f  + p * w;
    p = -0.00125372503f  + p * w;
    p = -0.00417768164f  + p * w;
    p =  0.246640727f    + p * w;
    p =  1.50140941f     + p * w;
  } else {
    w = sqrtf(w) - 3.0f;
    p = -0.000200214257f;
    p =  0.000100950558f + p * w;
    p =  0.00134934322f  + p * w;
    p = -0.00367342844f  + p * w;
    p =  0.00573950773f  + p * w;
    p = -0.0076224613f   + p * w;
    p =  0.00943887047f  + p * w;
    p =  1.00167406f     + p * w;
    p =  2.83297682f     + p * w;
  }
  return p * x;
}

__device__ __forceinline__ float u01(uint32_t b) {
#pragma clang fp contract(off)
  return __uint_as_float((b >> 9) | 0x3f800000u) - 1.0f;
}

// noise(t,e): depends only on key and element index — precomputable
__device__ __forceinline__ float noise_from(uint32_t k0, uint32_t k1, uint32_t e) {
#pragma clang fp contract(off)
  const float LO = -0x1.fffffep-1f;          // nextafter(-1, 0)
  const float SQRT2 = 1.4142135623730951f;
  uint32_t b0, b1; tf2x32(k0, k1, 0u, e, b0, b1);
  float un = u01(b0 ^ b1);
  float x = un * 2.0f + LO;
  x = fmaxf(LO, x);
  float nrm = SQRT2 * erfinv_f32(x);
  return nrm * 0.1f;
}

// spike uniform(t,e): also precomputable
__device__ __forceinline__ float us_from(uint32_t k0, uint32_t k1, uint32_t e) {
#pragma clang fp contract(off)
  uint32_t c0, c1; tf2x32(k0, k1, 0u, e, c0, c1);
  return fmaxf(0.0f, u01(c0 ^ c1));
}

// ---- per-step key derivation: keys = split(key(42), 200); kn,ks = split ----
__global__ void keys_kernel(uint4* __restrict__ gK) {
  int t = blockIdx.x * blockDim.x + threadIdx.x;
  if (t >= TSTEPS) return;
  uint32_t K0, K1; tf2x32(0u, 42u, 0u, (uint32_t)t, K0, K1);
  uint32_t n0, n1; tf2x32(K0, K1, 0u, 0u, n0, n1);   // k_noise
  uint32_t s0, s1; tf2x32(K0, K1, 0u, 1u, s0, s1);   // k_spike
  gK[t] = make_uint4(n0, n1, s0, s1);
}

__global__ __launch_bounds__(256) void lif_kernel(
    const float* __restrict__ gI,
    const float* __restrict__ gV0, const float* __restrict__ gT0,
    const float* __restrict__ gA0, const float* __restrict__ gS0,
    const float* __restrict__ gN0,
    const uint4* __restrict__ gK,
    float* __restrict__ gOut)
{
#pragma clang fp contract(off)
  const uint32_t e = blockIdx.x * 256u + threadIdx.x;

  float V  = gV0[e];
  float Th = gT0[e];
  float Ad = gA0[e];
  float Sy = gS0[e];
  float Nm = gN0[e];

  const float* Ip = gI + e;
  float* So = gOut + e;          // spikes as 0.0/1.0 float
  float* Vo = gOut + TBN + e;    // voltages

  // ---- prologue: precompute step-0 randoms + load I(0) ----
  uint4 kk0 = gK[0];
  uint32_t a0 = __builtin_amdgcn_readfirstlane(kk0.x);
  uint32_t a1 = __builtin_amdgcn_readfirstlane(kk0.y);
  uint32_t a2 = __builtin_amdgcn_readfirstlane(kk0.z);
  uint32_t a3 = __builtin_amdgcn_readfirstlane(kk0.w);
  float noise_c = noise_from(a0, a1, e);
  float us_c    = us_from(a2, a3, e);
  float I_c     = Ip[0];
  Ip += BN;

  for (int t = 0; t < TSTEPS - 1; ++t) {
    // ---- phase A (independent): randoms for step t+1, prefetch I(t+1) ----
    uint4 kk = gK[t + 1];
    uint32_t k0 = __builtin_amdgcn_readfirstlane(kk.x);
    uint32_t k1 = __builtin_amdgcn_readfirstlane(kk.y);
    uint32_t k2 = __builtin_amdgcn_readfirstlane(kk.z);
    uint32_t k3 = __builtin_amdgcn_readfirstlane(kk.w);
    float noise_n = noise_from(k0, k1, e);
    float us_n    = us_from(k2, k3, e);
    float I_n     = Ip[0];
    Ip += BN;

    // ---- phase B (serial chain): step t state update ----
    float Ieff = (I_c * Sy + Nm) - Ad;
    V = (V + (Ieff - V) * 0.05f) + noise_c;
    float md = Th - V;                       // == -(V - Th), bit-exact
    float ex = expf(md);
    float p = 1.0f / (1.0f + ex);
    bool spk = us_c < p;
    float sf = spk ? 1.0f : 0.0f;

    V = spk ? 0.0f : V;
    float thn = Th - 0.1f * (Th - 1.0f);
    Th = spk ? (Th + 0.1f) : thn;
    Th = fminf(fmaxf(Th, 0.5f), 2.0f);
    Ad = Ad * 0.9f + 0.5f * sf;
    Sy = Sy * (1.0f - 0.1f * sf) + 0.05f * (1.0f - Sy);

    __builtin_nontemporal_store(sf, So);
    __builtin_nontemporal_store(V,  Vo);
    So += BN; Vo += BN;

    noise_c = noise_n; us_c = us_n; I_c = I_n;
  }

  // ---- epilogue: final step (t = TSTEPS-1), serial only ----
  {
    float Ieff = (I_c * Sy + Nm) - Ad;
    V = (V + (Ieff - V) * 0.05f) + noise_c;
    float md = Th - V;
    float ex = expf(md);
    float p = 1.0f / (1.0f + ex);
    bool spk = us_c < p;
    float sf = spk ? 1.0f : 0.0f;
    V = spk ? 0.0f : V;
    __builtin_nontemporal_store(sf, So);
    __builtin_nontemporal_store(V,  Vo);
  }
}

extern "C" void kernel_launch(void* const* d_in, const int* in_sizes, int n_in,
                              void* d_out, int out_size, void* d_ws, size_t ws_size,
                              hipStream_t stream) {
  const float* I    = (const float*)d_in[0];
  const float* V0   = (const float*)d_in[1];
  const float* Vth0 = (const float*)d_in[2];
  const float* ad0  = (const float*)d_in[3];
  const float* sy0  = (const float*)d_in[4];
  const float* nm0  = (const float*)d_in[5];
  float* out = (float*)d_out;
  uint4* ktab = (uint4*)d_ws;   // 200 * 16 B = 3.2 KB of workspace

  keys_kernel<<<1, 256, 0, stream>>>(ktab);
  lif_kernel<<<BN / 256, 256, 0, stream>>>(I, V0, Vth0, ad0, sy0, nm0, ktab, out);
}